// Round 12
// baseline (141.623 us; speedup 1.0000x reference)
//
#include <hip/hip_runtime.h>

typedef unsigned long long u64;
typedef unsigned int u32;
typedef unsigned short u16;

#define MSORT 4096     // fallback sort capacity (power of 2)
#define TPBF  1024     // fallback / select kernel threads
#define BOXCAP 3648    // fallback: boxes staged in LDS (57 KB)
#define RSLOT_W 10     // fallback: register slots per wave
#define KPC   300      // kept recorded per class
#define SELCAP 1024
#define PREFR 64       // prefix-NMS rank budget (top-64 per class)
#define CMAX  256      // max classes supported by scatter LDS counters

#define WG_SCOPE __HIP_MEMORY_SCOPE_WORKGROUP

__device__ __forceinline__ float boxArea(float4 b) {
    return __fmul_rn(__fsub_rn(b.z, b.x), __fsub_rn(b.w, b.y));
}

// exact numpy f32 semantics: RN32(inter/uni) > T  <=>  inter (cmp) B*uni in f64
template<bool GE>
__device__ __forceinline__ bool iou_gt(float4 a, float area_a, float4 b, float area_b, double B) {
    float ix1 = fmaxf(a.x, b.x), iy1 = fmaxf(a.y, b.y);
    float ix2 = fminf(a.z, b.z), iy2 = fminf(a.w, b.w);
    float iw  = fmaxf(__fsub_rn(ix2, ix1), 0.0f);
    float ih  = fmaxf(__fsub_rn(iy2, iy1), 0.0f);
    float inter = __fmul_rn(iw, ih);
    float uni   = __fsub_rn(__fadd_rn(area_a, area_b), inter);
    return GE ? ((double)inter >= B * (double)uni) : ((double)inter > B * (double)uni);
}

// monotone bin of a positive-float score's bit pattern (11 bits @ exp 126)
__device__ __forceinline__ int scoreBin(u32 bits) {
    int b = (int)(bits >> 12) - 0x3F000;
    return b < 0 ? 0 : (b > 2047 ? 2047 : b);
}

// ---------------------------------------------------------------------------
// Kernel A: coalesced scatter. Each block reads a contiguous row-chunk of the
// row-major scores matrix (fully coalesced), counts valid (>conf) per class
// in LDS, reserves per-class global ranges (one atomicAdd/class/block), and
// scatters keys (score_bits<<32 | idx) to per-class lists. Within-class order
// is arbitrary — the key is a total order; downstream never needs input order.
// ---------------------------------------------------------------------------
__global__ __launch_bounds__(256, 1) void nms_scatter_kernel(
    const float* __restrict__ scores, const float* __restrict__ conf_ptr,
    int N, int C, int rpb, u32* __restrict__ gCnt, u64* __restrict__ gCand)
{
    __shared__ int cnt[CMAX];
    __shared__ int base[CMAX];
    const int tid = threadIdx.x;
    const int r0 = blockIdx.x * rpb;
    if (r0 >= N) return;
    const int r1 = (r0 + rpb < N) ? r0 + rpb : N;
    const int nel = (r1 - r0) * C;
    const float* sp = scores + (size_t)r0 * C;
    const float conf = *conf_ptr;

    for (int i = tid; i < C; i += 256) cnt[i] = 0;
    __syncthreads();
    for (int f = tid; f < nel; f += 256) {
        float s = sp[f];
        int cls = f % C;
        if (cls > 0 && s > conf) atomicAdd(&cnt[cls], 1);
    }
    __syncthreads();
    for (int i = tid; i < C; i += 256) {
        int n = cnt[i];
        base[i] = (i > 0 && n > 0) ? (int)atomicAdd(&gCnt[i], (u32)n) : 0;
        cnt[i] = 0;
    }
    __syncthreads();
    for (int f = tid; f < nel; f += 256) {
        float s = sp[f];
        int cls = f % C;
        if (cls > 0 && s > conf) {
            int off = atomicAdd(&cnt[cls], 1);
            int i = r0 + f / C;
            gCand[(size_t)(cls - 1) * N + base[cls] + off] =
                ((u64)__float_as_uint(s) << 32) | (u32)i;
        }
    }
}

// ---------------------------------------------------------------------------
// wave-0 prefix greedy NMS over the top-R (R<=64) candidates, one per lane.
// Exact: greedy decisions for rank j depend only on kept ranks < j.
// ---------------------------------------------------------------------------
template<bool GE>
__device__ __forceinline__ int prefix_nms_w0(
    const float* __restrict__ bboxes, const u64* __restrict__ sorted,
    int R, double B, int tid, int c, int N, u64* __restrict__ gkept_c)
{
    u64 key = (tid < R) ? sorted[tid] : 0;
    float4 bx = make_float4(0.f, 0.f, 0.f, 0.f);
    if (tid < R) bx = ((const float4*)bboxes)[(u32)key];
    float ar = boxArea(bx);
    u64 supB = (R >= 64) ? 0ull : (~0ull << R);
    int nk = 0;
    int i = -1;
    for (;;) {
        u64 mask = (i >= 63) ? 0ull : (~0ull << (i + 1));
        u64 alive = ~supB & mask;
        if (!alive) break;
        i = (int)__builtin_ctzll(alive);
        float4 bi;
        bi.x = __shfl(bx.x, i, 64); bi.y = __shfl(bx.y, i, 64);
        bi.z = __shfl(bx.z, i, 64); bi.w = __shfl(bx.w, i, 64);
        float ai = boxArea(bi);
        if (tid == 0) {
            u64 ki = sorted[i];
            u32 flat = (u32)c * (u32)N + (u32)ki;   // top_k ties: lower flat first
            gkept_c[nk] = (ki & 0xFFFFFFFF00000000ull) | (u32)(~flat);
        }
        nk++;
        bool sup = (tid > i) && iou_gt<GE>(bi, ai, bx, ar, B);
        supB |= __ballot(sup);
    }
    return nk;
}

// ---------------------------------------------------------------------------
// Kernel B: per class — reads its COALESCED candidate list, histogram top-65
// threshold, compact <=256, rank-by-count (1 barrier), prefix-NMS top-64 ->
// exact kept'. LAST block (ticket) computes theta lower bound + needFull.
// ---------------------------------------------------------------------------
__global__ __launch_bounds__(TPBF, 1) void nms_select_kernel(
    const float* __restrict__ bboxes, const float* __restrict__ nms_ptr,
    int N, int Mout, const u64* __restrict__ gCand, const u32* __restrict__ gCnt,
    u64* __restrict__ gkept, u32* __restrict__ g65, u32* __restrict__ gPre,
    u32* __restrict__ gCtl, u32* __restrict__ gTick)
{
    __shared__ u32 hist[2048];
    __shared__ u64 keybuf[256];
    __shared__ u64 sorted[66];
    __shared__ int chunk[64];
    __shared__ int ncollS, bstarS, nkS, lastS;
    __shared__ u32 thetaS;

    const int tid = threadIdx.x;
    const int c   = blockIdx.x;
    const int nc  = gridDim.x;
    const float nmsT = *nms_ptr;
    const int K = (int)gCnt[c + 1];
    const u64* cand = gCand + (size_t)c * N;

    for (int b = tid; b < 2048; b += TPBF) hist[b] = 0;
    if (tid < 66) sorted[tid] = 0;
    if (tid == 0) { ncollS = 0; nkS = 0; }
    __syncthreads();

    for (int t = tid; t < K; t += TPBF)
        atomicAdd(&hist[scoreBin((u32)(cand[t] >> 32))], 1u);
    __syncthreads();
    const int target = K < (PREFR + 1) ? K : (PREFR + 1);

    if (tid < 64) {
        int s = 0;
        #pragma unroll
        for (int b = 0; b < 32; b++) s += (int)hist[tid * 32 + b];
        chunk[tid] = s;
    }
    __syncthreads();
    if (tid == 0) {
        int acc = 0, ch = 63;
        for (; ch >= 0; ch--) { if (acc + chunk[ch] >= target) break; acc += chunk[ch]; }
        int bs = 0;
        if (ch >= 0) {
            int b = (ch << 5) + 31;
            for (; b >= (ch << 5); b--) { acc += (int)hist[b]; if (acc >= target) break; }
            bs = (b < (ch << 5)) ? (ch << 5) : b;
        }
        bstarS = bs;
    }
    __syncthreads();
    const u32 tbits = (bstarS == 0) ? 0u : (((u32)bstarS + 0x3F000u) << 12);

    for (int t = tid; t < K; t += TPBF) {
        u64 k = cand[t];
        if ((u32)(k >> 32) >= tbits) {
            int pos = atomicAdd(&ncollS, 1);
            if (pos < 256) keybuf[pos] = k;
        }
    }
    __syncthreads();
    const int ncoll = ncollS;
    const bool pre = (ncoll > 256);
    for (int p = ncoll + tid; p < 256; p += TPBF) keybuf[p] = 0;
    __syncthreads();

    u64* gkept_c = gkept + (size_t)c * KPC;
    if (!pre) {
        if (tid < 256) {                       // rank-by-count (unique keys)
            u64 my = keybuf[tid];
            int rank = 0;
            for (int j = 0; j < 256; j++) rank += (keybuf[j] > my);
            if (my && rank < PREFR + 1) sorted[rank] = my;
        }
        __syncthreads();
        const u32 tb = __float_as_uint(nmsT);
        const float Tn = __uint_as_float(tb + 1u);
        const double B = ((double)nmsT + (double)Tn) * 0.5;
        const bool geCmp = (((tb + 1u) & 1u) == 0u);
        if (tid < 64) {
            int R = ncoll < PREFR ? ncoll : PREFR;
            int nk = geCmp ? prefix_nms_w0<true >(bboxes, sorted, R, B, tid, c, N, gkept_c)
                           : prefix_nms_w0<false>(bboxes, sorted, R, B, tid, c, N, gkept_c);
            if (tid == 0) nkS = nk;
        }
        __syncthreads();
        for (int p = nkS + tid; p < KPC; p += TPBF) gkept_c[p] = 0;
    } else {
        for (int p = tid; p < KPC; p += TPBF) gkept_c[p] = 0;
    }
    if (tid == 0) {
        g65[c]  = pre ? 0xFFFFFFFFu : ((ncoll >= PREFR + 1) ? (u32)(sorted[PREFR] >> 32) : 0u);
        gPre[c] = pre ? 1u : 0u;
    }
    __syncthreads();

    // ---- ticket; last block runs the theta phase
    if (tid == 0) {
        __threadfence();
        u32 old = atomicAdd(gTick, 1u);
        lastS = (old == (u32)(nc - 1)) ? 1 : 0;
    }
    __syncthreads();
    if (!lastS) return;
    __threadfence();

    for (int b = tid; b < 2048; b += TPBF) hist[b] = 0;
    __syncthreads();
    const int total = nc * KPC;
    for (int t = tid; t < total; t += TPBF) {
        u64 k = gkept[t];
        if (k) atomicAdd(&hist[scoreBin((u32)(k >> 32))], 1u);
    }
    __syncthreads();
    if (tid < 64) {
        int s = 0;
        #pragma unroll
        for (int b = 0; b < 32; b++) s += (int)hist[tid * 32 + b];
        chunk[tid] = s;
    }
    __syncthreads();
    if (tid == 0) {
        int tot = 0;
        for (int ch = 0; ch < 64; ch++) tot += chunk[ch];
        u32 theta = 0u;
        if (tot >= Mout) {
            int acc = 0, ch = 63;
            for (; ch >= 0; ch--) { if (acc + chunk[ch] >= Mout) break; acc += chunk[ch]; }
            int b = (ch << 5) + 31;
            for (; b >= (ch << 5); b--) { acc += (int)hist[b]; if (acc >= Mout) break; }
            int bs = (b < (ch << 5)) ? (ch << 5) : b;
            theta = (bs <= 0) ? 0u : (((u32)bs + 0x3F000u) << 12);
        }
        gCtl[0] = theta;
        thetaS  = theta;
    }
    __syncthreads();
    const u32 theta = thetaS;
    for (int c2 = tid; c2 < nc; c2 += TPBF) {
        u32 need = gPre[c2];
        if ((int)gCnt[c2 + 1] > PREFR && g65[c2] >= theta) need = 1u;
        gCtl[1 + c2] = need;
    }
}

// ---------------------------------------------------------------------------
// Fallback greedy (lazy producer/consumer, 4 waves) with stop at theta.
// Scores come from the sorted keys in gsk_c (no scores[] access).
// ---------------------------------------------------------------------------
template<bool GE>
__device__ __forceinline__ u64 sweep_own(
    float4 bi, float area_i, const float4 (&breg)[RSLOT_W],
    const float (&areaj)[RSLOT_W], const float4* __restrict__ boxesLds,
    int base, int nslots, int lane, double B)
{
    u64 ns = 0;
    #pragma unroll
    for (int t = 0; t < RSLOT_W; t++)
        ns |= ((u64)iou_gt<GE>(bi, area_i, breg[t], areaj[t], B)) << (base + t);
    for (int t = RSLOT_W; t < nslots; t++) {
        float4 bj = boxesLds[((base + t) << 6) | lane];
        ns |= ((u64)iou_gt<GE>(bi, area_i, bj, boxArea(bj), B)) << (base + t);
    }
    return ns;
}

template<bool GE>
__device__ __forceinline__ int greedy_full(
    const float4* __restrict__ boxesLds, u16* __restrict__ keptR,
    float4* __restrict__ pubBox, u32* __restrict__ ctl,
    const u64* __restrict__ gsk_c, u32 thetaBits,
    int K, int smax, double B, int lane, int wave)
{
    const int SW   = (smax + 3) >> 2;
    const int base = (wave * SW < smax) ? wave * SW : smax;
    const int end  = (base + SW < smax) ? base + SW : smax;
    const int nslots = end - base;

    float4 breg[RSLOT_W];
    float  areaj[RSLOT_W];
    #pragma unroll
    for (int t = 0; t < RSLOT_W; t++) {
        float4 b = boxesLds[((base + t) << 6) | lane];
        breg[t] = b;
        areaj[t] = boxArea(b);
    }

    u64 sup;
    {
        int t = (lane < K) ? ((K - lane + 63) >> 6) : 0;
        sup = (t >= 64) ? 0ull : (~0ull << t);
    }

    u32 seen = 0;
    if (wave != 0) {
        for (;;) {
            u32 d  = __hip_atomic_load(&ctl[2], __ATOMIC_ACQUIRE, WG_SCOPE);
            u32 cn = __hip_atomic_load(&ctl[0], __ATOMIC_ACQUIRE, WG_SCOPE);
            bool prog = (seen < cn);
            while (seen < cn) {
                float4 bi = pubBox[seen]; seen++;
                sup |= sweep_own<GE>(bi, boxArea(bi), breg, areaj, boxesLds, base, nslots, lane, B);
            }
            if (d) return -1;
            u32 aw = __hip_atomic_load(&ctl[1], __ATOMIC_ACQUIRE, WG_SCOPE);
            if (aw == (u32)wave) {
                u32 cn2 = __hip_atomic_load(&ctl[0], __ATOMIC_ACQUIRE, WG_SCOPE);
                while (seen < cn2) {
                    float4 bi = pubBox[seen]; seen++;
                    sup |= sweep_own<GE>(bi, boxArea(bi), breg, areaj, boxesLds, base, nslots, lane, B);
                }
                break;
            }
            if (!prog) __builtin_amdgcn_s_sleep(1);
        }
    }

    u32 nk = seen;
    const u32 seen0 = seen;
    int scur = base - 1;
    float4 bcur = make_float4(0.f, 0.f, 0.f, 0.f);
    float  acur = 0.f;
    int js = base << 6;

    for (;;) {
        int s = js >> 6;
        while (s > scur) {
            scur++;
            if (scur < end) {
                bcur = boxesLds[(scur << 6) | lane];
                acur = boxArea(bcur);
                u64 bit = 0;
                for (u32 k = seen0; k < nk; k++) {
                    float4 bk = pubBox[k];
                    bit |= ((u64)iou_gt<GE>(bk, boxArea(bk), bcur, acur, B));
                }
                sup |= bit << scur;
            }
        }
        if (scur >= end) {
            if (wave == 3) {
                if (lane == 0) __hip_atomic_store(&ctl[2], 1u, __ATOMIC_RELEASE, WG_SCOPE);
                return (int)nk;
            }
            if (lane == 0) __hip_atomic_store(&ctl[1], (u32)(wave + 1), __ATOMIC_RELEASE, WG_SCOPE);
            return -1;
        }
        u64 bal = __ballot((int)(((~sup) >> scur) & 1ull)) & (~0ull << (js & 63));
        if (bal == 0) { js = (scur + 1) << 6; continue; }
        int i = (scur << 6) + (int)__builtin_ctzll(bal);

        if (thetaBits && (u32)(gsk_c[i] >> 32) < thetaBits) {  // below theta: done
            if (lane == 0) __hip_atomic_store(&ctl[2], 1u, __ATOMIC_RELEASE, WG_SCOPE);
            return (int)nk;
        }
        float4 bi = boxesLds[i];
        if (lane == 0) { pubBox[nk] = bi; keptR[nk] = (u16)i; }
        nk++;
        if (nk >= KPC) {
            if (lane == 0) {
                __hip_atomic_store(&ctl[0], nk, __ATOMIC_RELEASE, WG_SCOPE);
                __hip_atomic_store(&ctl[2], 1u, __ATOMIC_RELEASE, WG_SCOPE);
            }
            return (int)nk;
        }
        if (lane == 0) __hip_atomic_store(&ctl[0], nk, __ATOMIC_RELEASE, WG_SCOPE);
        sup |= ((u64)iou_gt<GE>(bi, boxArea(bi), bcur, acur, B)) << scur;
        js = i + 1;
    }
}

// ---------------------------------------------------------------------------
// Kernel C: full per-class NMS for flagged classes only (sort from gCand,
// coalesced); LAST block (ticket) runs the global top-Mout inline.
// ---------------------------------------------------------------------------
__global__ __launch_bounds__(TPBF, 1) void nms_full_kernel(
    const float* __restrict__ bboxes, const float* __restrict__ nms_ptr,
    int N, int Mout, const u64* __restrict__ gCand, const u32* __restrict__ gCnt,
    const u32* __restrict__ gCtl, u64* __restrict__ gsk, u64* __restrict__ gkept,
    u32* __restrict__ gTick, float* __restrict__ out)
{
    __shared__ __align__(16) char smem[63856];
    __shared__ int lastS, selCount, bstar2S;

    const int tid = threadIdx.x;
    const int c   = blockIdx.x;
    const int nc  = gridDim.x;

    if (gCtl[1 + c] != 0u) {
        u64*    sortbuf  = (u64*)smem;             // [0,32768)
        float4* boxesLds = (float4*)smem;          // [0,58368)
        u16*    keptR    = (u16*)(smem + 58368);
        u32*    ctl      = (u32*)(smem + 58976);
        float4* pubBox   = (float4*)(smem + 58992);
        const float nmsT = *nms_ptr;
        const u32 thetaBits = gCtl[0];
        const u64* cand = gCand + (size_t)c * N;

        int K = (int)gCnt[c + 1];
        if (K > MSORT) K = MSORT;                  // matches prior rounds' cap
        for (int p = tid; p < K; p += TPBF) sortbuf[p] = cand[p];   // coalesced
        int M = 64; while (M < K) M <<= 1;
        for (int p = K + tid; p < M; p += TPBF) sortbuf[p] = 0;
        __syncthreads();
        for (int kk = 2; kk <= M; kk <<= 1) {
            for (int j = kk >> 1; j > 0; j >>= 1) {
                for (int i = tid; i < M; i += TPBF) {
                    int ixj = i ^ j;
                    if (ixj > i) {
                        u64 a = sortbuf[i], b = sortbuf[ixj];
                        if (((i & kk) == 0) ? (a < b) : (a > b)) { sortbuf[i] = b; sortbuf[ixj] = a; }
                    }
                }
                __syncthreads();
            }
        }
        if (K > BOXCAP) K = BOXCAP;
        u64 myKey[MSORT / TPBF];
        #pragma unroll
        for (int t = 0; t < MSORT / TPBF; t++) myKey[t] = sortbuf[t * TPBF + tid];
        __syncthreads();
        u64* gsk_c = gsk + (size_t)c * BOXCAP;
        #pragma unroll
        for (int t = 0; t < MSORT / TPBF; t++) {
            int r = t * TPBF + tid;
            if (r < K) {
                gsk_c[r] = myKey[t];
                boxesLds[r] = ((const float4*)bboxes)[(u32)myKey[t]];
            }
        }
        if (tid == 0) { ctl[0] = 0; ctl[1] = 0; ctl[2] = 0; }
        __syncthreads();

        if (tid < 256) {
            const int lane = tid & 63;
            const int wave = tid >> 6;
            const u32 tb = __float_as_uint(nmsT);
            const float Tn = __uint_as_float(tb + 1u);
            const double B = ((double)nmsT + (double)Tn) * 0.5;
            const bool geCmp = (((tb + 1u) & 1u) == 0u);
            const int smax = (K + 63) >> 6;
            int ret = geCmp ? greedy_full<true >(boxesLds, keptR, pubBox, ctl, gsk_c, thetaBits, K, smax, B, lane, wave)
                            : greedy_full<false>(boxesLds, keptR, pubBox, ctl, gsk_c, thetaBits, K, smax, B, lane, wave);
            if (ret >= 0) {
                int kept = ret; if (kept > KPC) kept = KPC;
                u64* gkept_c = gkept + (size_t)c * KPC;
                for (int p = lane; p < kept; p += 64) {
                    u64 key = gsk_c[keptR[p]];
                    u32 flat = (u32)c * (u32)N + (u32)key;
                    gkept_c[p] = (key & 0xFFFFFFFF00000000ull) | (u32)(~flat);
                }
                for (int p = kept + lane; p < KPC; p += 64) gkept_c[p] = 0;
            }
        }
    }
    __syncthreads();

    // ---- ticket; last block runs global top-Mout
    if (tid == 0) {
        __threadfence();
        u32 old = atomicAdd(gTick, 1u);
        lastS = (old == (u32)(nc - 1)) ? 1 : 0;
    }
    __syncthreads();
    if (!lastS) return;
    __threadfence();

    u32* hist  = (u32*)smem;               // 8 KB
    int* chunk = (int*)(smem + 8192);      // 256 B
    u64* sel   = (u64*)(smem + 8448);      // 8 KB

    const int total = nc * KPC;
    for (int b = tid; b < 2048; b += TPBF) hist[b] = 0;
    if (tid == 0) selCount = 0;
    __syncthreads();
    for (int t = tid; t < total; t += TPBF) {
        u64 k = gkept[t];
        if (k) atomicAdd(&hist[scoreBin((u32)(k >> 32))], 1u);
    }
    __syncthreads();
    if (tid < 64) {
        int s = 0;
        #pragma unroll
        for (int b = 0; b < 32; b++) s += (int)hist[tid * 32 + b];
        chunk[tid] = s;
    }
    __syncthreads();
    if (tid == 0) {
        int acc = 0, ch = 63;
        for (; ch >= 0; ch--) { if (acc + chunk[ch] >= Mout) break; acc += chunk[ch]; }
        int bs = 0;
        if (ch >= 0) {
            int b = (ch << 5) + 31;
            for (; b >= (ch << 5); b--) { acc += (int)hist[b]; if (acc >= Mout) break; }
            bs = (b < (ch << 5)) ? (ch << 5) : b;
        }
        bstar2S = bs;
    }
    __syncthreads();
    const int bstar = bstar2S;
    for (int t = tid; t < total; t += TPBF) {
        u64 k = gkept[t];
        if (k && scoreBin((u32)(k >> 32)) >= bstar) {
            int p = atomicAdd(&selCount, 1);
            if (p < SELCAP) sel[p] = k;
        }
    }
    __syncthreads();
    int cnt = selCount; if (cnt > SELCAP) cnt = SELCAP;
    int SM = 512; while (SM < cnt) SM <<= 1;       // runtime-sized (>= Mout)
    for (int p = cnt + tid; p < SM; p += TPBF) sel[p] = 0;
    __syncthreads();
    for (int kk = 2; kk <= SM; kk <<= 1) {
        for (int j = kk >> 1; j > 0; j >>= 1) {
            for (int i = tid; i < SM; i += TPBF) {
                int ixj = i ^ j;
                if (ixj > i) {
                    u64 a = sel[i], b = sel[ixj];
                    if (((i & kk) == 0) ? (a < b) : (a > b)) { sel[i] = b; sel[ixj] = a; }
                }
            }
            __syncthreads();
        }
    }

    for (int t = tid; t < Mout; t += TPBF) {
        u64 k = (t < SM) ? sel[t] : 0;
        float px1 = 0.f, py1 = 0.f, px2 = 0.f, py2 = 0.f, ps = 0.f, plab = -1.0f;
        if (k) {
            float s  = __uint_as_float((u32)(k >> 32));
            u32 flat = ~((u32)k);
            int cc   = (int)(flat / (u32)N);
            int box  = (int)(flat - (u32)cc * (u32)N);
            float4 bb = ((const float4*)bboxes)[box];
            px1 = bb.x; py1 = bb.y; px2 = bb.z; py2 = bb.w; ps = s;
            plab = (float)(cc + 1);
        }
        out[t * 5 + 0] = px1;
        out[t * 5 + 1] = py1;
        out[t * 5 + 2] = px2;
        out[t * 5 + 3] = py2;
        out[t * 5 + 4] = ps;
        out[Mout * 5 + t] = plab;
    }
}

extern "C" void kernel_launch(void* const* d_in, const int* in_sizes, int n_in,
                              void* d_out, int out_size, void* d_ws, size_t ws_size,
                              hipStream_t stream) {
    const float* bboxes = (const float*)d_in[0];
    const float* scores = (const float*)d_in[1];
    const float* conf   = (const float*)d_in[2];
    const float* nmsT   = (const float*)d_in[3];

    const int N    = in_sizes[0] / 4;        // 5000
    const int C    = in_sizes[1] / N;        // 81
    const int nc   = C - 1;                  // 80
    const int Mout = out_size / 6;           // 300

    // ws layout (8B-aligned):
    char* wsb = (char*)d_ws;
    size_t off = 0;
    u64* gCand = (u64*)(wsb + off); off += (size_t)nc * N * sizeof(u64);       // 3.2 MB
    u64* gsk   = (u64*)(wsb + off); off += (size_t)nc * BOXCAP * sizeof(u64);  // 2.3 MB
    u64* gkept = (u64*)(wsb + off); off += (size_t)nc * KPC * sizeof(u64);     // 192 KB
    u32* g65   = (u32*)(wsb + off); off += (size_t)((nc + 1) & ~1) * sizeof(u32);
    u32* gPre  = (u32*)(wsb + off); off += (size_t)((nc + 1) & ~1) * sizeof(u32);
    u32* gCtl  = (u32*)(wsb + off); off += (size_t)((nc + 2) & ~1) * sizeof(u32);
    u32* gCnt  = (u32*)(wsb + off);          // C counters + 2 tickets, contiguous
    u32* gTick = gCnt + C;

    hipMemsetAsync(gCnt, 0, (C + 2) * sizeof(u32), stream);
    const int rpb = 40;                      // rows per scatter block
    const int nbA = (N + rpb - 1) / rpb;     // 125 blocks
    nms_scatter_kernel<<<nbA, 256, 0, stream>>>(scores, conf, N, C, rpb, gCnt, gCand);
    nms_select_kernel<<<nc, TPBF, 0, stream>>>(bboxes, nmsT, N, Mout, gCand, gCnt,
                                               gkept, g65, gPre, gCtl, gTick);
    nms_full_kernel<<<nc, TPBF, 0, stream>>>(bboxes, nmsT, N, Mout, gCand, gCnt,
                                             gCtl, gsk, gkept, gTick + 1, (float*)d_out);
}

// Round 13
// 117.280 us; speedup vs baseline: 1.2076x; 1.2076x over previous
//
#include <hip/hip_runtime.h>

typedef unsigned long long u64;
typedef unsigned int u32;
typedef unsigned short u16;

#define MSORT 4096     // fallback sort capacity (power of 2)
#define TPB1  1024     // select kernel threads
#define TPBF  1024     // fallback kernel threads
#define BOXCAP 3648    // fallback: boxes staged in LDS (57 KB)
#define KCAP  3072     // select: single-pass key capacity in LDS (24 KB)
#define RSLOT_W 10     // fallback: register slots per wave
#define KPC   300      // kept recorded per class
#define SELCAP 1024
#define PREFR 64       // prefix-NMS rank budget (top-64 per class)

#define WG_SCOPE __HIP_MEMORY_SCOPE_WORKGROUP

__device__ __forceinline__ float boxArea(float4 b) {
    return __fmul_rn(__fsub_rn(b.z, b.x), __fsub_rn(b.w, b.y));
}

// exact numpy f32 semantics: RN32(inter/uni) > T  <=>  inter (cmp) B*uni in f64
template<bool GE>
__device__ __forceinline__ bool iou_gt(float4 a, float area_a, float4 b, float area_b, double B) {
    float ix1 = fmaxf(a.x, b.x), iy1 = fmaxf(a.y, b.y);
    float ix2 = fminf(a.z, b.z), iy2 = fminf(a.w, b.w);
    float iw  = fmaxf(__fsub_rn(ix2, ix1), 0.0f);
    float ih  = fmaxf(__fsub_rn(iy2, iy1), 0.0f);
    float inter = __fmul_rn(iw, ih);
    float uni   = __fsub_rn(__fadd_rn(area_a, area_b), inter);
    return GE ? ((double)inter >= B * (double)uni) : ((double)inter > B * (double)uni);
}

// monotone bin of a positive-float score's bit pattern (11 bits @ exp 126)
__device__ __forceinline__ int scoreBin(u32 bits) {
    int b = (int)(bits >> 12) - 0x3F000;
    return b < 0 ? 0 : (b > 2047 ? 2047 : b);
}

// ---------------------------------------------------------------------------
// wave-0 prefix greedy NMS over the top-R (R<=64) candidates, one per lane.
// Exact: greedy decisions for rank j depend only on kept ranks < j.
// ---------------------------------------------------------------------------
template<bool GE>
__device__ __forceinline__ int prefix_nms_w0(
    const float* __restrict__ bboxes, const u64* __restrict__ sorted,
    int R, double B, int tid, int c, int N, u64* __restrict__ gkept_c)
{
    u64 key = (tid < R) ? sorted[tid] : 0;
    float4 bx = make_float4(0.f, 0.f, 0.f, 0.f);
    if (tid < R) bx = ((const float4*)bboxes)[(u32)key];
    float ar = boxArea(bx);
    u64 supB = (R >= 64) ? 0ull : (~0ull << R);
    int nk = 0;
    int i = -1;
    for (;;) {
        u64 mask = (i >= 63) ? 0ull : (~0ull << (i + 1));
        u64 alive = ~supB & mask;
        if (!alive) break;
        i = (int)__builtin_ctzll(alive);
        float4 bi;
        bi.x = __shfl(bx.x, i, 64); bi.y = __shfl(bx.y, i, 64);
        bi.z = __shfl(bx.z, i, 64); bi.w = __shfl(bx.w, i, 64);
        float ai = boxArea(bi);
        if (tid == 0) {
            u64 ki = sorted[i];
            u32 flat = (u32)c * (u32)N + (u32)ki;   // top_k ties: lower flat first
            gkept_c[nk] = (ki & 0xFFFFFFFF00000000ull) | (u32)(~flat);
        }
        nk++;
        bool sup = (tid > i) && iou_gt<GE>(bi, ai, bx, ar, B);
        supB |= __ballot(sup);
    }
    return nk;
}

// ---------------------------------------------------------------------------
// Kernel 1: per class — ONE strided pass over scores (keys -> LDS +
// histogram), top-65 threshold from histogram, compact <=256 from LDS,
// rank-by-count (1 barrier), prefix-NMS top-64 -> exact kept' subset.
// ---------------------------------------------------------------------------
__global__ __launch_bounds__(TPB1, 1) void nms_select_kernel(
    const float* __restrict__ bboxes, const float* __restrict__ scores,
    const float* __restrict__ conf_ptr, const float* __restrict__ nms_ptr,
    int N, int C, u64* __restrict__ gkept,
    u32* __restrict__ gK, u32* __restrict__ g65, u32* __restrict__ gPre)
{
    __shared__ u64 keys[KCAP];            // 24 KB
    __shared__ u32 hist[2048];            // 8 KB
    __shared__ u64 keybuf[256];
    __shared__ u64 sorted[66];
    __shared__ int chunk[64];
    __shared__ int cntS, ncollS, bstarS, nkS;

    const int tid = threadIdx.x;
    const int c   = blockIdx.x;
    const int cls = c + 1;
    const float conf = *conf_ptr;
    const float nmsT = *nms_ptr;

    for (int b = tid; b < 2048; b += TPB1) hist[b] = 0;
    if (tid < 66) sorted[tid] = 0;
    if (tid == 0) { cntS = 0; ncollS = 0; nkS = 0; }
    __syncthreads();

    // ---- single strided pass: collect keys + histogram
    for (int i = tid; i < N; i += TPB1) {
        float s = scores[(size_t)i * C + cls];
        if (s > conf) {
            int p = atomicAdd(&cntS, 1);
            if (p < KCAP) keys[p] = ((u64)__float_as_uint(s) << 32) | (u32)i;
            atomicAdd(&hist[scoreBin(__float_as_uint(s))], 1u);
        }
    }
    __syncthreads();
    const int K = cntS;
    const bool preOv = (K > KCAP);
    const int target = K < (PREFR + 1) ? K : (PREFR + 1);

    if (tid < 64) {
        int s = 0;
        #pragma unroll
        for (int b = 0; b < 32; b++) s += (int)hist[tid * 32 + b];
        chunk[tid] = s;
    }
    __syncthreads();
    if (tid == 0) {
        int acc = 0, ch = 63;
        for (; ch >= 0; ch--) { if (acc + chunk[ch] >= target) break; acc += chunk[ch]; }
        int bs = 0;
        if (ch >= 0) {
            int b = (ch << 5) + 31;
            for (; b >= (ch << 5); b--) { acc += (int)hist[b]; if (acc >= target) break; }
            bs = (b < (ch << 5)) ? (ch << 5) : b;
        }
        bstarS = bs;
    }
    __syncthreads();
    const u32 tbits = (bstarS == 0) ? 0u : (((u32)bstarS + 0x3F000u) << 12);

    // ---- compact top candidates from LDS keys (no 2nd global pass)
    const int KL = K < KCAP ? K : KCAP;
    for (int p = tid; p < KL; p += TPB1) {
        u64 k = keys[p];
        if ((u32)(k >> 32) >= tbits) {
            int pos = atomicAdd(&ncollS, 1);
            if (pos < 256) keybuf[pos] = k;
        }
    }
    __syncthreads();
    const int ncoll = ncollS;
    const bool pre = preOv || (ncoll > 256);
    for (int p = ncoll + tid; p < 256; p += TPB1) keybuf[p] = 0;
    __syncthreads();

    u64* gkept_c = gkept + (size_t)c * KPC;
    if (!pre) {
        if (tid < 256) {                       // rank-by-count (keys are unique)
            u64 my = keybuf[tid];
            int rank = 0;
            for (int j = 0; j < 256; j++) rank += (keybuf[j] > my);
            if (my && rank < PREFR + 1) sorted[rank] = my;
        }
        __syncthreads();
        const u32 tb = __float_as_uint(nmsT);
        const float Tn = __uint_as_float(tb + 1u);
        const double B = ((double)nmsT + (double)Tn) * 0.5;
        const bool geCmp = (((tb + 1u) & 1u) == 0u);
        if (tid < 64) {
            int R = ncoll < PREFR ? ncoll : PREFR;
            int nk = geCmp ? prefix_nms_w0<true >(bboxes, sorted, R, B, tid, c, N, gkept_c)
                           : prefix_nms_w0<false>(bboxes, sorted, R, B, tid, c, N, gkept_c);
            if (tid == 0) nkS = nk;
        }
        __syncthreads();
        for (int p = nkS + tid; p < KPC; p += TPB1) gkept_c[p] = 0;
    } else {
        for (int p = tid; p < KPC; p += TPB1) gkept_c[p] = 0;
    }
    if (tid == 0) {
        gK[c]   = (u32)K;
        g65[c]  = pre ? 0xFFFFFFFFu : ((ncoll >= PREFR + 1) ? (u32)(sorted[PREFR] >> 32) : 0u);
        gPre[c] = pre ? 1u : 0u;
    }
}

// ---------------------------------------------------------------------------
// Kernel 2: pool kept' -> theta lower bound (bin edge of Mout-th largest),
// per-class needFull flags. gCtl[0]=thetaBits, gCtl[1+c]=needFull.
// ---------------------------------------------------------------------------
__global__ __launch_bounds__(1024) void nms_theta_kernel(
    const u64* __restrict__ gkept, const u32* __restrict__ gK,
    const u32* __restrict__ g65, const u32* __restrict__ gPre,
    int nc, int Mout, u32* __restrict__ gCtl)
{
    __shared__ u32 hist[2048];
    __shared__ int chunk[64];
    __shared__ u32 thetaS;
    const int tid = threadIdx.x;
    const int total = nc * KPC;
    for (int b = tid; b < 2048; b += 1024) hist[b] = 0;
    __syncthreads();
    for (int t = tid; t < total; t += 1024) {
        u64 k = gkept[t];
        if (k) atomicAdd(&hist[scoreBin((u32)(k >> 32))], 1u);
    }
    __syncthreads();
    if (tid < 64) {
        int s = 0;
        #pragma unroll
        for (int b = 0; b < 32; b++) s += (int)hist[tid * 32 + b];
        chunk[tid] = s;
    }
    __syncthreads();
    if (tid == 0) {
        int tot = 0;
        for (int ch = 0; ch < 64; ch++) tot += chunk[ch];
        u32 theta = 0u;
        if (tot >= Mout) {
            int acc = 0, ch = 63;
            for (; ch >= 0; ch--) { if (acc + chunk[ch] >= Mout) break; acc += chunk[ch]; }
            int b = (ch << 5) + 31;
            for (; b >= (ch << 5); b--) { acc += (int)hist[b]; if (acc >= Mout) break; }
            int bs = (b < (ch << 5)) ? (ch << 5) : b;
            theta = (bs <= 0) ? 0u : (((u32)bs + 0x3F000u) << 12);
        }
        gCtl[0] = theta;
        thetaS  = theta;
    }
    __syncthreads();
    const u32 theta = thetaS;
    for (int c2 = tid; c2 < nc; c2 += 1024) {
        u32 need = gPre[c2];
        if (gK[c2] > PREFR && g65[c2] >= theta) need = 1u;   // theta==0 -> always
        gCtl[1 + c2] = need;
    }
}

// ---------------------------------------------------------------------------
// Fallback greedy (lazy producer/consumer, 4 waves) with stop at theta.
// ---------------------------------------------------------------------------
template<bool GE>
__device__ __forceinline__ u64 sweep_own(
    float4 bi, float area_i, const float4 (&breg)[RSLOT_W],
    const float (&areaj)[RSLOT_W], const float4* __restrict__ boxesLds,
    int base, int nslots, int lane, double B)
{
    u64 ns = 0;
    #pragma unroll
    for (int t = 0; t < RSLOT_W; t++)
        ns |= ((u64)iou_gt<GE>(bi, area_i, breg[t], areaj[t], B)) << (base + t);
    for (int t = RSLOT_W; t < nslots; t++) {
        float4 bj = boxesLds[((base + t) << 6) | lane];
        ns |= ((u64)iou_gt<GE>(bi, area_i, bj, boxArea(bj), B)) << (base + t);
    }
    return ns;
}

template<bool GE>
__device__ __forceinline__ int greedy_full(
    const float4* __restrict__ boxesLds, u16* __restrict__ keptR,
    float4* __restrict__ pubBox, u32* __restrict__ ctl,
    const u32* __restrict__ gsi_c, const float* __restrict__ scores,
    int cls, int C, u32 thetaBits,
    int K, int smax, double B, int lane, int wave)
{
    const int SW   = (smax + 3) >> 2;
    const int base = (wave * SW < smax) ? wave * SW : smax;
    const int end  = (base + SW < smax) ? base + SW : smax;
    const int nslots = end - base;

    float4 breg[RSLOT_W];
    float  areaj[RSLOT_W];
    #pragma unroll
    for (int t = 0; t < RSLOT_W; t++) {
        float4 b = boxesLds[((base + t) << 6) | lane];
        breg[t] = b;
        areaj[t] = boxArea(b);
    }

    u64 sup;
    {
        int t = (lane < K) ? ((K - lane + 63) >> 6) : 0;
        sup = (t >= 64) ? 0ull : (~0ull << t);
    }

    u32 seen = 0;
    if (wave != 0) {
        for (;;) {
            u32 d  = __hip_atomic_load(&ctl[2], __ATOMIC_ACQUIRE, WG_SCOPE);
            u32 cn = __hip_atomic_load(&ctl[0], __ATOMIC_ACQUIRE, WG_SCOPE);
            bool prog = (seen < cn);
            while (seen < cn) {
                float4 bi = pubBox[seen]; seen++;
                sup |= sweep_own<GE>(bi, boxArea(bi), breg, areaj, boxesLds, base, nslots, lane, B);
            }
            if (d) return -1;
            u32 aw = __hip_atomic_load(&ctl[1], __ATOMIC_ACQUIRE, WG_SCOPE);
            if (aw == (u32)wave) {
                u32 cn2 = __hip_atomic_load(&ctl[0], __ATOMIC_ACQUIRE, WG_SCOPE);
                while (seen < cn2) {
                    float4 bi = pubBox[seen]; seen++;
                    sup |= sweep_own<GE>(bi, boxArea(bi), breg, areaj, boxesLds, base, nslots, lane, B);
                }
                break;
            }
            if (!prog) __builtin_amdgcn_s_sleep(1);
        }
    }

    u32 nk = seen;
    const u32 seen0 = seen;
    int scur = base - 1;
    float4 bcur = make_float4(0.f, 0.f, 0.f, 0.f);
    float  acur = 0.f;
    int js = base << 6;

    for (;;) {
        int s = js >> 6;
        while (s > scur) {
            scur++;
            if (scur < end) {
                bcur = boxesLds[(scur << 6) | lane];
                acur = boxArea(bcur);
                u64 bit = 0;
                for (u32 k = seen0; k < nk; k++) {
                    float4 bk = pubBox[k];
                    bit |= ((u64)iou_gt<GE>(bk, boxArea(bk), bcur, acur, B));
                }
                sup |= bit << scur;
            }
        }
        if (scur >= end) {
            if (wave == 3) {
                if (lane == 0) __hip_atomic_store(&ctl[2], 1u, __ATOMIC_RELEASE, WG_SCOPE);
                return (int)nk;
            }
            if (lane == 0) __hip_atomic_store(&ctl[1], (u32)(wave + 1), __ATOMIC_RELEASE, WG_SCOPE);
            return -1;
        }
        u64 bal = __ballot((int)(((~sup) >> scur) & 1ull)) & (~0ull << (js & 63));
        if (bal == 0) { js = (scur + 1) << 6; continue; }
        int i = (scur << 6) + (int)__builtin_ctzll(bal);

        if (thetaBits) {
            u32 idx = gsi_c[i];
            float sc = scores[(size_t)idx * C + cls];
            if (__float_as_uint(sc) < thetaBits) {
                if (lane == 0) __hip_atomic_store(&ctl[2], 1u, __ATOMIC_RELEASE, WG_SCOPE);
                return (int)nk;
            }
        }
        float4 bi = boxesLds[i];
        if (lane == 0) { pubBox[nk] = bi; keptR[nk] = (u16)i; }
        nk++;
        if (nk >= KPC) {
            if (lane == 0) {
                __hip_atomic_store(&ctl[0], nk, __ATOMIC_RELEASE, WG_SCOPE);
                __hip_atomic_store(&ctl[2], 1u, __ATOMIC_RELEASE, WG_SCOPE);
            }
            return (int)nk;
        }
        if (lane == 0) __hip_atomic_store(&ctl[0], nk, __ATOMIC_RELEASE, WG_SCOPE);
        sup |= ((u64)iou_gt<GE>(bi, boxArea(bi), bcur, acur, B)) << scur;
        js = i + 1;
    }
}

// ---------------------------------------------------------------------------
// Kernel 3: full per-class NMS for flagged classes only (sort @1024 thr,
// greedy on waves 0-3). Fast classes return immediately.
// ---------------------------------------------------------------------------
__global__ __launch_bounds__(TPBF, 1) void nms_full_kernel(
    const float* __restrict__ bboxes, const float* __restrict__ scores,
    const float* __restrict__ conf_ptr, const float* __restrict__ nms_ptr,
    int N, int C, const u32* __restrict__ gCtl,
    u32* __restrict__ gsi, u64* __restrict__ gkept)
{
    const int c = blockIdx.x;
    if (gCtl[1 + c] == 0u) return;

    __shared__ __align__(16) char smem[63856];
    u64*    sortbuf  = (u64*)smem;             // [0,32768)
    float4* boxesLds = (float4*)smem;          // [0,58368)
    u16*    keptR    = (u16*)(smem + 58368);
    u32*    ctl      = (u32*)(smem + 58976);
    float4* pubBox   = (float4*)(smem + 58992);
    __shared__ int cntS;

    const int tid = threadIdx.x;
    const int cls = c + 1;
    const float conf = *conf_ptr;
    const float nmsT = *nms_ptr;
    const u32 thetaBits = gCtl[0];

    if (tid == 0) cntS = 0;
    __syncthreads();
    for (int i = tid; i < N; i += TPBF) {
        float s = scores[(size_t)i * C + cls];
        if (s > conf) {
            int p = atomicAdd(&cntS, 1);
            if (p < MSORT) sortbuf[p] = ((u64)__float_as_uint(s) << 32) | (u32)i;
        }
    }
    __syncthreads();
    int K = cntS; if (K > BOXCAP) K = BOXCAP;
    int M = 64; while (M < K) M <<= 1;
    for (int p = K + tid; p < M; p += TPBF) sortbuf[p] = 0;
    __syncthreads();
    for (int kk = 2; kk <= M; kk <<= 1) {
        for (int j = kk >> 1; j > 0; j >>= 1) {
            for (int i = tid; i < M; i += TPBF) {
                int ixj = i ^ j;
                if (ixj > i) {
                    u64 a = sortbuf[i], b = sortbuf[ixj];
                    if (((i & kk) == 0) ? (a < b) : (a > b)) { sortbuf[i] = b; sortbuf[ixj] = a; }
                }
            }
            __syncthreads();
        }
    }
    u32 myIdx[MSORT / TPBF];
    #pragma unroll
    for (int t = 0; t < MSORT / TPBF; t++) myIdx[t] = (u32)sortbuf[t * TPBF + tid];
    __syncthreads();
    u32* gsi_c = gsi + (size_t)c * BOXCAP;
    #pragma unroll
    for (int t = 0; t < MSORT / TPBF; t++) {
        int r = t * TPBF + tid;
        if (r < K) {
            u32 idx = myIdx[t];
            gsi_c[r] = idx;
            boxesLds[r] = ((const float4*)bboxes)[idx];
        }
    }
    if (tid == 0) { ctl[0] = 0; ctl[1] = 0; ctl[2] = 0; }
    __syncthreads();
    if (tid >= 256) return;

    const int lane = tid & 63;
    const int wave = tid >> 6;
    const u32 tb = __float_as_uint(nmsT);
    const float Tn = __uint_as_float(tb + 1u);
    const double B = ((double)nmsT + (double)Tn) * 0.5;
    const bool geCmp = (((tb + 1u) & 1u) == 0u);
    const int smax = (K + 63) >> 6;

    int ret = geCmp ? greedy_full<true >(boxesLds, keptR, pubBox, ctl, gsi_c, scores, cls, C, thetaBits, K, smax, B, lane, wave)
                    : greedy_full<false>(boxesLds, keptR, pubBox, ctl, gsi_c, scores, cls, C, thetaBits, K, smax, B, lane, wave);
    if (ret >= 0) {
        int kept = ret; if (kept > KPC) kept = KPC;
        u64* gkept_c = gkept + (size_t)c * KPC;
        for (int p = lane; p < kept; p += 64) {
            int rank = keptR[p];
            u32 idx = gsi_c[rank];
            float sc = scores[(size_t)idx * C + cls];
            u32 flat = (u32)c * (u32)N + idx;
            gkept_c[p] = ((u64)__float_as_uint(sc) << 32) | (u32)(~flat);
        }
        for (int p = kept + lane; p < KPC; p += 64) gkept_c[p] = 0;
    }
}

// ---------------------------------------------------------------------------
// Kernel 4: global top-Mout over nc*KPC kept keys (runtime-sized bitonic).
// ---------------------------------------------------------------------------
__global__ __launch_bounds__(1024) void nms_topk_kernel(
    const float* __restrict__ bboxes, const u64* __restrict__ gkept,
    int N, int nc, int Mout, float* __restrict__ out)
{
    __shared__ u32 hist[2048];
    __shared__ int chunk[64];
    __shared__ int selCount;
    __shared__ int bstarS;
    __shared__ u64 sel[SELCAP];

    const int tid = threadIdx.x;
    const int total = nc * KPC;

    for (int b = tid; b < 2048; b += 1024) hist[b] = 0;
    if (tid == 0) selCount = 0;
    __syncthreads();

    for (int t = tid; t < total; t += 1024) {
        u64 k = gkept[t];
        if (k) atomicAdd(&hist[scoreBin((u32)(k >> 32))], 1u);
    }
    __syncthreads();

    if (tid < 64) {
        int s = 0;
        #pragma unroll
        for (int b = 0; b < 32; b++) s += (int)hist[tid * 32 + b];
        chunk[tid] = s;
    }
    __syncthreads();

    if (tid == 0) {
        int acc = 0, ch = 63;
        for (; ch >= 0; ch--) {
            if (acc + chunk[ch] >= Mout) break;
            acc += chunk[ch];
        }
        int bs = 0;
        if (ch >= 0) {
            int b = (ch << 5) + 31;
            for (; b >= (ch << 5); b--) { acc += (int)hist[b]; if (acc >= Mout) break; }
            bs = (b < (ch << 5)) ? (ch << 5) : b;
        }
        bstarS = bs;
    }
    __syncthreads();
    const int bstar = bstarS;

    for (int t = tid; t < total; t += 1024) {
        u64 k = gkept[t];
        if (k && scoreBin((u32)(k >> 32)) >= bstar) {
            int p = atomicAdd(&selCount, 1);
            if (p < SELCAP) sel[p] = k;
        }
    }
    __syncthreads();
    int cnt = selCount; if (cnt > SELCAP) cnt = SELCAP;
    int SM = 512; while (SM < cnt) SM <<= 1;       // runtime-sized (>= Mout)
    for (int p = cnt + tid; p < SM; p += 1024) sel[p] = 0;
    __syncthreads();

    for (int kk = 2; kk <= SM; kk <<= 1) {
        for (int j = kk >> 1; j > 0; j >>= 1) {
            for (int i = tid; i < SM; i += 1024) {
                int ixj = i ^ j;
                if (ixj > i) {
                    u64 a = sel[i], b = sel[ixj];
                    if (((i & kk) == 0) ? (a < b) : (a > b)) { sel[i] = b; sel[ixj] = a; }
                }
            }
            __syncthreads();
        }
    }

    for (int t = tid; t < Mout; t += 1024) {
        u64 k = (t < SM) ? sel[t] : 0;
        float px1 = 0.f, py1 = 0.f, px2 = 0.f, py2 = 0.f, ps = 0.f, plab = -1.0f;
        if (k) {
            float s  = __uint_as_float((u32)(k >> 32));
            u32 flat = ~((u32)k);
            int cc   = (int)(flat / (u32)N);
            int box  = (int)(flat - (u32)cc * (u32)N);
            float4 bb = ((const float4*)bboxes)[box];
            px1 = bb.x; py1 = bb.y; px2 = bb.z; py2 = bb.w; ps = s;
            plab = (float)(cc + 1);
        }
        out[t * 5 + 0] = px1;
        out[t * 5 + 1] = py1;
        out[t * 5 + 2] = px2;
        out[t * 5 + 3] = py2;
        out[t * 5 + 4] = ps;
        out[Mout * 5 + t] = plab;
    }
}

extern "C" void kernel_launch(void* const* d_in, const int* in_sizes, int n_in,
                              void* d_out, int out_size, void* d_ws, size_t ws_size,
                              hipStream_t stream) {
    const float* bboxes = (const float*)d_in[0];
    const float* scores = (const float*)d_in[1];
    const float* conf   = (const float*)d_in[2];
    const float* nmsT   = (const float*)d_in[3];

    const int N    = in_sizes[0] / 4;        // 5000
    const int C    = in_sizes[1] / N;        // 81
    const int nc   = C - 1;                  // 80
    const int Mout = out_size / 6;           // 300

    // ws layout: [gsi: nc*BOXCAP u32][gkept: nc*KPC u64][gK|g65|gPre|gCtl u32]
    char* wsb = (char*)d_ws;
    size_t off = 0;
    u32* gsi   = (u32*)(wsb + off); off += (size_t)nc * BOXCAP * sizeof(u32);
    u64* gkept = (u64*)(wsb + off); off += (size_t)nc * KPC * sizeof(u64);
    u32* gK    = (u32*)(wsb + off); off += (size_t)((nc + 1) & ~1) * sizeof(u32);
    u32* g65   = (u32*)(wsb + off); off += (size_t)((nc + 1) & ~1) * sizeof(u32);
    u32* gPre  = (u32*)(wsb + off); off += (size_t)((nc + 1) & ~1) * sizeof(u32);
    u32* gCtl  = (u32*)(wsb + off);

    nms_select_kernel<<<nc, TPB1, 0, stream>>>(bboxes, scores, conf, nmsT, N, C, gkept, gK, g65, gPre);
    nms_theta_kernel<<<1, 1024, 0, stream>>>(gkept, gK, g65, gPre, nc, Mout, gCtl);
    nms_full_kernel<<<nc, TPBF, 0, stream>>>(bboxes, scores, conf, nmsT, N, C, gCtl, gsi, gkept);
    nms_topk_kernel<<<1, 1024, 0, stream>>>(bboxes, gkept, N, nc, Mout, (float*)d_out);
}